// Round 13
// baseline (247.481 us; speedup 1.0000x reference)
//
#include <hip/hip_runtime.h>
#include <stdint.h>

typedef __attribute__((ext_vector_type(4)))  float    f32x4;
typedef __attribute__((ext_vector_type(16))) float    f32x16;
typedef __attribute__((ext_vector_type(8)))  _Float16 f16x8;
typedef __attribute__((ext_vector_type(8)))  __bf16   bf16x8;

#define SEQ   2048
#define DH    64
#define BQ    256            // q rows per block (4 q-waves x 64)
#define BK    64             // keys per tile
#define NT    (SEQ / BK)     // 32 k-tiles per batch
#define HNT   (NT / 2)       // 16 tiles per key-half (split-K factor 2)
#define TILEE (64 * 64)      // 4096 elems per tile (fragment-major: 8 frags x 64 lanes x 8)
#define L2E   1.44269504088896340736f

#if __has_builtin(__builtin_amdgcn_exp2f)
static __device__ __forceinline__ float fast_exp2(float x) { return __builtin_amdgcn_exp2f(x); }
#else
static __device__ __forceinline__ float fast_exp2(float x) {
  float r; asm("v_exp_f32 %0, %1" : "=v"(r) : "v"(x)); return r;
}
#endif
static __device__ __forceinline__ uint32_t pack2_bf16(float a, float b) {
  union { __bf16 h[2]; uint32_t u; } cv;
  cv.h[0] = (__bf16)a; cv.h[1] = (__bf16)b;
  return cv.u;
}
union frag_u { uint32_t u[4]; bf16x8 v; };

// sigma relabel: S^T=K*Q^T's C-layout row m (= b+4h+8c) is made to carry key
// sigma(m) = 16*(c&1) + 8*h + 4*(c>>1) + b. Then each lane's 16 C-values are
// exactly the natural-key-order A-fragment slices for P*V — the C->A transform
// is pure register repacking (HW-verified: absmax 0.03125).
__host__ __device__ inline int sigma32(int m) {
  int b = m & 3, h = (m >> 2) & 1, c = m >> 3;
  return ((c & 1) << 4) | (h << 3) | ((c >> 1) << 2) | b;
}

// ---------------- pre-pass (verbatim from v12, proven): FRAGMENT-MAJOR tiles
// so the main kernel's register-direct fragment loads are perfectly coalesced
// (lane i reads 16B at base + i*16 — one segment per wave load).
__global__ __launch_bounds__(256)
void prepass(const float* __restrict__ K, const float* __restrict__ V,
             _Float16* __restrict__ Kh, __bf16* __restrict__ Vh) {
  const int blk = blockIdx.x;
  const int tid = threadIdx.x;
  if (blk < 32 * NT) {
    const float* src = K + ((size_t)(blk >> 5) * SEQ + (size_t)(blk & 31) * 64) * DH;
    _Float16*    dst = Kh + (size_t)blk * TILEE;
#pragma unroll
    for (int it = 0; it < 2; ++it) {
      const int c  = tid + it * 256;         // output chunk 0..511 (16B each)
      const int f  = c >> 6, ln = c & 63;
      const int ks = f >> 1, rh = f & 1;
      const int srow = rh * 32 + sigma32(ln & 31);
      const int scol = ks * 16 + (ln >> 5) * 8;
      const float* sp = src + srow * DH + scol;
      f32x4 a = *(const f32x4*)(sp + 0), b = *(const f32x4*)(sp + 4);
      f16x8 h;
#pragma unroll
      for (int j = 0; j < 4; ++j) { h[j] = (_Float16)a[j]; h[j + 4] = (_Float16)b[j]; }
      *(f16x8*)(dst + (size_t)c * 8) = h;    // coalesced: thread t -> chunk t
    }
  } else {
    const int blk2 = blk - 32 * NT;
    const float* src = V + ((size_t)(blk2 >> 5) * SEQ + (size_t)(blk2 & 31) * 64) * DH;
    __bf16*      dst = Vh + (size_t)blk2 * TILEE;
#pragma unroll
    for (int it = 0; it < 2; ++it) {
      const int c  = tid + it * 256;
      const int f  = c >> 6, ln = c & 63;
      const int ks = f >> 1, dh = f & 1;
      const int key0 = ks * 16 + (ln >> 5) * 8;
      const int d    = dh * 32 + (ln & 31);
      const float* sp = src + (size_t)key0 * DH + d;   // 8 rows, d coalesced across lanes
      __bf16 hv[8];
#pragma unroll
      for (int j = 0; j < 8; ++j) hv[j] = (__bf16)sp[(size_t)j * DH];
      *(bf16x8*)(dst + (size_t)c * 8) = *(bf16x8*)hv;  // coalesced write
    }
  }
}

// ---------------- main v15: 64 q-rows per wave (2 q-groups sharing one K/V
// fetch) -> per-work VMEM bytes halved (the v12/v14 convergence at ~58us is
// consistent with L1-return-BW saturation from per-wave-redundant K/V loads).
// Split-K x2 in-block (8 waves: qw 0-3 x key-half) restores 2048 waves =
// 2/SIMD, the residency v12 proved. Phase order keeps one s-pair live at a
// time -> peak ~244 VGPR; __launch_bounds__(512,1) = 256 cap (1 blk/CU).
__global__ __launch_bounds__(512, 1)
void flash_attn_v15(const float* __restrict__ Q, const _Float16* __restrict__ Kh,
                    const __bf16* __restrict__ Vh, float* __restrict__ O) {
  __shared__ float accL[4][64][17];      // 17.4 KB chunked-combine buffer (17-pad: conflict-free)
  __shared__ float sumL[4][2][64];       // upper-half partial rowsums per q-group
  __shared__ float Ls[4][2][32];         // per (qwave, group) 1/rowsum broadcast

  const int tid  = threadIdx.x;
  const int wv   = tid >> 6;             // 0..7
  const int qw   = wv & 3;               // q-wave: which 64 q-rows
  const int kh   = wv >> 2;              // key-half: 0 -> tiles 0..15, 1 -> 16..31
  const int lane = tid & 63;
  const int hfw  = lane >> 5;
  const int l31  = lane & 31;

  const int batch = blockIdx.x & 31;     // batch-major: all 8 q-blocks of a batch
  const int qblk  = blockIdx.x >> 5;     // land on one XCD -> K/V tiles L2-resident

  const float* Qb = Q + (size_t)batch * SEQ * DH;
  float*       Ob = O + (size_t)batch * SEQ * DH;
  // fragment-major per-lane bases: lane's chunk of frag f is at f*512 + lane*8
  const _Float16* Kb = Kh + (size_t)batch * NT * TILEE + lane * 8;
  const __bf16*   Vb = Vh + (size_t)batch * NT * TILEE + lane * 8;

  // Q fragments, 2 groups: lane holds Q[q = qw*64 + g*32 + l31][d=ks*16+hfw*8+j]
  f16x8 qf0[4], qf1[4];
  {
#pragma unroll
    for (int g = 0; g < 2; ++g) {
      const int qrow = qblk * BQ + qw * 64 + g * 32 + l31;
      const float* qp = Qb + (size_t)qrow * DH + hfw * 8;
      f16x8* qf = g ? qf1 : qf0;
#pragma unroll
      for (int ks = 0; ks < 4; ++ks) {
        f32x4 a = *(const f32x4*)(qp + ks * 16);
        f32x4 b = *(const f32x4*)(qp + ks * 16 + 4);
#pragma unroll
        for (int j = 0; j < 4; ++j) {
          qf[ks][j]     = (_Float16)(a[j] * L2E);
          qf[ks][j + 4] = (_Float16)(b[j] * L2E);
        }
      }
    }
  }

  f32x16 acc00 = {}, acc01 = {};   // group 0: d = l31 / l31+32
  f32x16 acc10 = {}, acc11 = {};   // group 1
  float lsum0 = 0.f, lsum1 = 0.f;  // partial row-sums per group (q = l31 of group)

  auto loadK = [&](int t, f16x8* kf) {
    const _Float16* p = Kb + (size_t)t * TILEE;
#pragma unroll
    for (int ks = 0; ks < 4; ++ks) {
      kf[ks]     = *(const f16x8*)(p + (2 * ks)     * 512);  // rh=0: keys 0..31
      kf[ks + 4] = *(const f16x8*)(p + (2 * ks + 1) * 512);  // rh=1: keys 32..63
    }
  };

  // exp2 + natural-key-order A-fragment repack (verbatim math from v12)
  auto expand = [&](const f32x16& sa, const f32x16& sb, frag_u* fr, float& ls) {
#pragma unroll
    for (int t2 = 0; t2 < 2; ++t2) {
      const f32x16& s = t2 ? sb : sa;
      float p[16];
#pragma unroll
      for (int j = 0; j < 16; ++j) p[j] = fast_exp2(s[j]);
      float a0 = (p[0] + p[1]) + (p[2] + p[3]);
      float a1 = (p[4] + p[5]) + (p[6] + p[7]);
      float a2 = (p[8] + p[9]) + (p[10] + p[11]);
      float a3 = (p[12] + p[13]) + (p[14] + p[15]);
      ls += (a0 + a1) + (a2 + a3);
      fr[2 * t2    ].u[0] = pack2_bf16(p[0],  p[1]);
      fr[2 * t2    ].u[1] = pack2_bf16(p[2],  p[3]);
      fr[2 * t2    ].u[2] = pack2_bf16(p[8],  p[9]);
      fr[2 * t2    ].u[3] = pack2_bf16(p[10], p[11]);
      fr[2 * t2 + 1].u[0] = pack2_bf16(p[4],  p[5]);
      fr[2 * t2 + 1].u[1] = pack2_bf16(p[6],  p[7]);
      fr[2 * t2 + 1].u[2] = pack2_bf16(p[12], p[13]);
      fr[2 * t2 + 1].u[3] = pack2_bf16(p[14], p[15]);
    }
  };

  const int t0   = kh * HNT;
  const int tEnd = t0 + HNT;

  // Phase order keeps only ONE s-pair live at a time (VGPR peak ~244):
  // V loads; QK g0; exp g0; PV g0; QK g1; K-prefetch; exp g1; PV g1.
  auto step = [&](int i, f16x8* kcur) {
    bf16x8 vf[8];
    {
      const __bf16* p = Vb + (size_t)i * TILEE;
#pragma unroll
      for (int ks = 0; ks < 4; ++ks) {
        vf[ks]     = *(const bf16x8*)(p + (2 * ks)     * 512);  // dh=0: d = l31
        vf[ks + 4] = *(const bf16x8*)(p + (2 * ks + 1) * 512);  // dh=1: d = l31+32
      }
    }

    // ---- group 0: S^T, exp, PV
    __builtin_amdgcn_s_setprio(1);
    f32x16 s00 = {}, s01 = {};
#pragma unroll
    for (int ks = 0; ks < 4; ++ks) {
      s00 = __builtin_amdgcn_mfma_f32_32x32x16_f16(kcur[ks],     qf0[ks], s00, 0, 0, 0);
      s01 = __builtin_amdgcn_mfma_f32_32x32x16_f16(kcur[ks + 4], qf0[ks], s01, 0, 0, 0);
    }
    __builtin_amdgcn_s_setprio(0);
    frag_u fr0[4];
    expand(s00, s01, fr0, lsum0);
    __builtin_amdgcn_s_setprio(1);
#pragma unroll
    for (int ks = 0; ks < 4; ++ks) {
      acc00 = __builtin_amdgcn_mfma_f32_32x32x16_bf16(fr0[ks].v, vf[ks],     acc00, 0, 0, 0);
      acc01 = __builtin_amdgcn_mfma_f32_32x32x16_bf16(fr0[ks].v, vf[ks + 4], acc01, 0, 0, 0);
    }

    // ---- group 1: S^T (last use of kcur), then prefetch K(i+2) into its slot
    f32x16 s10 = {}, s11 = {};
#pragma unroll
    for (int ks = 0; ks < 4; ++ks) {
      s10 = __builtin_amdgcn_mfma_f32_32x32x16_f16(kcur[ks],     qf1[ks], s10, 0, 0, 0);
      s11 = __builtin_amdgcn_mfma_f32_32x32x16_f16(kcur[ks + 4], qf1[ks], s11, 0, 0, 0);
    }
    __builtin_amdgcn_s_setprio(0);

    if (i + 2 < tEnd) loadK(i + 2, kcur);   // lands during next tile (full tile of cover)

    frag_u fr1[4];
    expand(s10, s11, fr1, lsum1);
    __builtin_amdgcn_s_setprio(1);
#pragma unroll
    for (int ks = 0; ks < 4; ++ks) {
      acc10 = __builtin_amdgcn_mfma_f32_32x32x16_bf16(fr1[ks].v, vf[ks],     acc10, 0, 0, 0);
      acc11 = __builtin_amdgcn_mfma_f32_32x32x16_bf16(fr1[ks].v, vf[ks + 4], acc11, 0, 0, 0);
    }
    __builtin_amdgcn_s_setprio(0);
  };

  // prologue: K(t0), K(t0+1) resident in regs before the loop
  f16x8 kA[8], kB[8];
  loadK(t0, kA);
  loadK(t0 + 1, kB);

#pragma unroll 1
  for (int i = t0; i < tEnd; i += 2) {   // HNT even: 2x unroll renames kA/kB
    step(i,     kA);
    step(i + 1, kB);
  }

  // ---- split-K combine (chunked through 17-pad LDS) + epilogue.
  float tot0 = lsum0 + __shfl_xor(lsum0, 32);
  float tot1 = lsum1 + __shfl_xor(lsum1, 32);
  if (kh == 1) { sumL[qw][0][lane] = tot0; sumL[qw][1][lane] = tot1; }

#define COMBINE_ROUND(ACC)                                                     \
  if (kh == 1) {                                                               \
    _Pragma("unroll") for (int j = 0; j < 16; ++j) accL[qw][lane][j] = ACC[j]; \
  }                                                                            \
  __syncthreads();                                                             \
  if (kh == 0) {                                                               \
    _Pragma("unroll") for (int j = 0; j < 16; ++j) ACC[j] += accL[qw][lane][j];\
  }                                                                            \
  __syncthreads();

  COMBINE_ROUND(acc00)
  COMBINE_ROUND(acc01)
  COMBINE_ROUND(acc10)
  COMBINE_ROUND(acc11)
#undef COMBINE_ROUND

  if (kh == 0) {
    float tt0 = tot0 + sumL[qw][0][lane];
    float tt1 = tot1 + sumL[qw][1][lane];
    Ls[qw][0][l31] = __builtin_amdgcn_rcpf(tt0);   // lanes l / l+32 write same value
    Ls[qw][1][l31] = __builtin_amdgcn_rcpf(tt1);
#pragma unroll
    for (int j = 0; j < 16; ++j) {
      const int row = (j & 3) + 8 * (j >> 2) + 4 * hfw;
      const float i0 = Ls[qw][0][row];
      const float i1 = Ls[qw][1][row];
      size_t off0 = (size_t)(qblk * BQ + qw * 64 + row) * DH + l31;        // group 0
      size_t off1 = (size_t)(qblk * BQ + qw * 64 + 32 + row) * DH + l31;   // group 1
      Ob[off0]      = acc00[j] * i0;
      Ob[off0 + 32] = acc01[j] * i0;
      Ob[off1]      = acc10[j] * i1;
      Ob[off1 + 32] = acc11[j] * i1;
    }
  }
}

extern "C" void kernel_launch(void* const* d_in, const int* in_sizes, int n_in,
                              void* d_out, int out_size, void* d_ws, size_t ws_size,
                              hipStream_t stream) {
  (void)in_sizes; (void)n_in; (void)ws_size; (void)out_size;
  const float* q = (const float*)d_in[0];
  const float* k = (const float*)d_in[1];
  const float* v = (const float*)d_in[2];
  float* o = (float*)d_out;
  // ws: Kh 8.39 MB | Vh 8.39 MB  (~16.8 MB total)
  _Float16* Kh = (_Float16*)d_ws;
  __bf16*   Vh = (__bf16*)((char*)d_ws + (size_t)32 * NT * TILEE * sizeof(_Float16));

  prepass<<<dim3(2 * 32 * NT), dim3(256), 0, stream>>>(k, v, Kh, Vh);
  flash_attn_v15<<<dim3(32 * (SEQ / BQ)), dim3(512), 0, stream>>>(q, Kh, Vh, o);
}

// Round 15
// 139.539 us; speedup vs baseline: 1.7736x; 1.7736x over previous
//
#include <hip/hip_runtime.h>
#include <stdint.h>

typedef __attribute__((ext_vector_type(4)))  float    f32x4;
typedef __attribute__((ext_vector_type(16))) float    f32x16;
typedef __attribute__((ext_vector_type(8)))  _Float16 f16x8;
typedef __attribute__((ext_vector_type(8)))  __bf16   bf16x8;

#define SEQ   2048
#define DH    64
#define BQ    128            // q rows per block (4 q-waves x 32)
#define BK    64             // keys per tile
#define NT    (SEQ / BK)     // 32 k-tiles per batch
#define HNT   (NT / 2)       // 16 tiles per key-half (split-K factor 2)
#define ROWE  72             // padded row: 144 B stride (16B-aligned, proven 0-conflict)
#define TILEE (64 * ROWE)    // 4608 elems = 9216 B per tile
#define L2E   1.44269504088896340736f

#if __has_builtin(__builtin_amdgcn_exp2f)
static __device__ __forceinline__ float fast_exp2(float x) { return __builtin_amdgcn_exp2f(x); }
#else
static __device__ __forceinline__ float fast_exp2(float x) {
  float r; asm("v_exp_f32 %0, %1" : "=v"(r) : "v"(x)); return r;
}
#endif
static __device__ __forceinline__ uint32_t pack2_bf16(float a, float b) {
  union { __bf16 h[2]; uint32_t u; } cv;
  cv.h[0] = (__bf16)a; cv.h[1] = (__bf16)b;
  return cv.u;
}
union frag_u { uint32_t u[4]; bf16x8 v; };

typedef const __attribute__((address_space(1))) uint32_t* gp1_t;
typedef __attribute__((address_space(3))) uint32_t*       lp3_t;

// sigma relabel (HW-verified): C-layout row m of S^T=K*Q^T carries key sigma(m).
__host__ __device__ inline int sigma32(int m) {
  int b = m & 3, h = (m >> 2) & 1, c = m >> 3;
  return ((c & 1) << 4) | (h << 3) | ((c >> 1) << 2) | b;
}

// ---------------- pre-pass (verbatim v10, proven): K -> f16 padded tiles with
// sigma row relabel; V -> bf16 transposed (natural key order) padded tiles
__global__ __launch_bounds__(256)
void prepass(const float* __restrict__ K, const float* __restrict__ V,
             _Float16* __restrict__ Kh, __bf16* __restrict__ Vh) {
  const int blk = blockIdx.x;
  const int tid = threadIdx.x;
  if (blk < 32 * NT) {
    const float* src = K + ((size_t)(blk >> 5) * SEQ + (size_t)(blk & 31) * 64) * DH;
    _Float16*    dst = Kh + (size_t)blk * TILEE;
    const int row = tid >> 2, c = (tid & 3) << 4;
    const int srow = (row & 32) | sigma32(row & 31);   // row holds key sigma(row)
    const float* sp = src + srow * DH + c;
    f32x4 x0 = *(const f32x4*)(sp + 0),  x1 = *(const f32x4*)(sp + 4);
    f32x4 x2 = *(const f32x4*)(sp + 8),  x3 = *(const f32x4*)(sp + 12);
    f16x8 h0, h1;
#pragma unroll
    for (int j = 0; j < 4; ++j) {
      h0[j] = (_Float16)x0[j]; h0[j + 4] = (_Float16)x1[j];
      h1[j] = (_Float16)x2[j]; h1[j + 4] = (_Float16)x3[j];
    }
    *(f16x8*)(dst + row * ROWE + c)     = h0;
    *(f16x8*)(dst + row * ROWE + c + 8) = h1;
  } else {
    const int blk2 = blk - 32 * NT;
    const float* src = V + ((size_t)(blk2 >> 5) * SEQ + (size_t)(blk2 & 31) * 64) * DH;
    __bf16*      dst = Vh + (size_t)blk2 * TILEE;
#pragma unroll
    for (int it = 0; it < 4; ++it) {
      int task = tid + it * 256;
      int d = task & 63, g = task >> 6;      // 16 key-groups x 64 d
      const float* sp = src + (size_t)(4 * g) * DH + d;   // coalesced across d
      __bf16 hv[4];
#pragma unroll
      for (int j = 0; j < 4; ++j) hv[j] = (__bf16)sp[(size_t)j * DH];
      *(uint64_t*)(dst + d * ROWE + 4 * g) = *(uint64_t*)hv;
    }
  }
}

// ---------------- main v16: v10's low-register LDS datapath (92+32acc <= 128
// -> 4 waves/SIMD CAN be resident) + in-block split-K x2 to put 4096 waves in
// the grid. Waves 0-3: key tiles 0..15 (own LDS dbuf); waves 4-7: 16..31.
// LDS 74KB x 2 blocks/CU = 148 <= 160. Combine reuses dead K-tile LDS.
__global__ __launch_bounds__(512, 2)
void flash_attn_v16(const float* __restrict__ Q, const _Float16* __restrict__ Kh,
                    const __bf16* __restrict__ Vh, float* __restrict__ O) {
  __shared__ _Float16 Ksb[2][2][64][ROWE];   // [key-half][dbuf] 36864 B
  __shared__ __bf16   Vtb[2][2][64][ROWE];   // 36864 B
  __shared__ float    Ls[4][32];             // per-qwave 1/rowsum broadcast

  const int tid  = threadIdx.x;
  const int wv   = tid >> 6;             // 0..7
  const int qw   = wv & 3;               // q-wave: which 32 q-rows
  const int kh   = wv >> 2;              // key-half: 0 -> tiles 0..15, 1 -> 16..31
  const int lane = tid & 63;
  const int hfw  = lane >> 5;
  const int l31  = lane & 31;

  const int batch = blockIdx.x & 31;     // batch-major for XCD L2 locality
  const int qblk  = blockIdx.x >> 5;     // 16 q-blocks of 128 rows

  const float* Qb = Q + (size_t)batch * SEQ * DH;
  float*       Ob = O + (size_t)batch * SEQ * DH;
  const uint32_t* Kt0 = (const uint32_t*)(Kh + (size_t)batch * NT * TILEE);
  const uint32_t* Vt0 = (const uint32_t*)(Vh + (size_t)batch * NT * TILEE);

  // DMA: wave-uniform LDS base (HW adds lane*16) — proven pattern. Each
  // key-half's 4 waves stage that half's tiles into its own buffers.
  auto stage = [&](int t, int buf) {
    const uint32_t* kgp = Kt0 + (size_t)t * (TILEE / 2);
    const uint32_t* vgp = Vt0 + (size_t)t * (TILEE / 2);
    lp3_t kl = (lp3_t)&Ksb[kh][buf][0][0];
    lp3_t vl = (lp3_t)&Vtb[kh][buf][0][0];
#pragma unroll
    for (int j = qw; j < 9; j += 4) {
      __builtin_amdgcn_global_load_lds((gp1_t)(kgp + j * 256 + lane * 4), kl + j * 256, 16, 0, 0);
      __builtin_amdgcn_global_load_lds((gp1_t)(vgp + j * 256 + lane * 4), vl + j * 256, 16, 0, 0);
    }
  };

  // Q fragments (B-operand of S^T): lane holds Q[q=l31][d=ks*16+hfw*8+j], *log2e
  const int qrow = qblk * BQ + qw * 32 + l31;
  f16x8 qf[4];
  {
    const float* qp = Qb + (size_t)qrow * DH + hfw * 8;
#pragma unroll
    for (int ks = 0; ks < 4; ++ks) {
      f32x4 a = *(const f32x4*)(qp + ks * 16);
      f32x4 b = *(const f32x4*)(qp + ks * 16 + 4);
#pragma unroll
      for (int j = 0; j < 4; ++j) {
        qf[ks][j]     = (_Float16)(a[j] * L2E);
        qf[ks][j + 4] = (_Float16)(b[j] * L2E);
      }
    }
  }

  f32x16 acc0 = {}, acc1 = {};   // O partial: col = d = l31 / l31+32, rows = q
  float lsum = 0.f;              // partial row-sum for q = l31 over this half's keys

  const int t0 = kh * HNT;
  stage(t0, 0);

#pragma unroll 1
  for (int li = 0; li < HNT; ++li) {
    __syncthreads();   // vmcnt(0) drain: tile t0+li resident; prior buf reads done
    if (li + 1 < HNT) stage(t0 + li + 1, (li + 1) & 1);
    const int buf = li & 1;

    // ---- S^T = K·Q^T (sigma-relabeled K rows): C col = q = l31, rows = keys
    __builtin_amdgcn_s_setprio(1);
    f32x16 s0 = {}, s1 = {};
#pragma unroll
    for (int ks = 0; ks < 4; ++ks) {
      int dof = ks * 16 + hfw * 8;
      f16x8 kf0 = *(const f16x8*)&Ksb[kh][buf][l31][dof];
      f16x8 kf1 = *(const f16x8*)&Ksb[kh][buf][l31 + 32][dof];
      s0 = __builtin_amdgcn_mfma_f32_32x32x16_f16(kf0, qf[ks], s0, 0, 0, 0);  // keys 0..31
      s1 = __builtin_amdgcn_mfma_f32_32x32x16_f16(kf1, qf[ks], s1, 0, 0, 0);  // keys 32..63
    }
    __builtin_amdgcn_s_setprio(0);

    // ---- P = exp2(S); repack into natural-key-order A-fragments (registers)
    frag_u fr[4];
#pragma unroll
    for (int t2 = 0; t2 < 2; ++t2) {
      const f32x16& s = t2 ? s1 : s0;
      float p[16];
#pragma unroll
      for (int j = 0; j < 16; ++j) p[j] = fast_exp2(s[j]);
      float a0 = (p[0] + p[1]) + (p[2] + p[3]);
      float a1 = (p[4] + p[5]) + (p[6] + p[7]);
      float a2 = (p[8] + p[9]) + (p[10] + p[11]);
      float a3 = (p[12] + p[13]) + (p[14] + p[15]);
      lsum += (a0 + a1) + (a2 + a3);
      fr[2 * t2    ].u[0] = pack2_bf16(p[0],  p[1]);
      fr[2 * t2    ].u[1] = pack2_bf16(p[2],  p[3]);
      fr[2 * t2    ].u[2] = pack2_bf16(p[8],  p[9]);
      fr[2 * t2    ].u[3] = pack2_bf16(p[10], p[11]);
      fr[2 * t2 + 1].u[0] = pack2_bf16(p[4],  p[5]);
      fr[2 * t2 + 1].u[1] = pack2_bf16(p[6],  p[7]);
      fr[2 * t2 + 1].u[2] = pack2_bf16(p[12], p[13]);
      fr[2 * t2 + 1].u[3] = pack2_bf16(p[14], p[15]);
    }

    // ---- O += P·V : A = P frags (registers), B = V^T (LDS, JIT reads)
    __builtin_amdgcn_s_setprio(1);
#pragma unroll
    for (int ks = 0; ks < 4; ++ks) {
      int kof = ks * 16 + hfw * 8;
      bf16x8 v0 = *(const bf16x8*)&Vtb[kh][buf][l31][kof];
      bf16x8 v1 = *(const bf16x8*)&Vtb[kh][buf][l31 + 32][kof];
      acc0 = __builtin_amdgcn_mfma_f32_32x32x16_bf16(fr[ks].v, v0, acc0, 0, 0, 0);
      acc1 = __builtin_amdgcn_mfma_f32_32x32x16_bf16(fr[ks].v, v1, acc1, 0, 0, 0);
    }
    __builtin_amdgcn_s_setprio(0);
  }

  // ---- split-K combine: exp2-partials are exactly additive. Reuse the dead
  // K/V LDS as the combine buffer (33-stride: lane-major -> conflict-free).
  float tot = lsum + __shfl_xor(lsum, 32);   // this half's full rowsum for q=l31
  __syncthreads();                           // all waves done with tile LDS
  float* cb = (float*)&Ksb[0][0][0][0];      // 4*64*33*4B = 33.8 KB <= 36.8 KB
  float* sb = (float*)&Vtb[0][0][0][0];      // 4*64*4B
  if (kh == 1) {
    const int base = (qw * 64 + lane) * 33;
#pragma unroll
    for (int j = 0; j < 16; ++j) {
      cb[base + j]      = acc0[j];
      cb[base + j + 16] = acc1[j];
    }
    sb[qw * 64 + lane] = tot;
  }
  __syncthreads();
  if (kh == 0) {
    const int base = (qw * 64 + lane) * 33;
    float tot2 = tot + sb[qw * 64 + lane];   // partner half, same q-rows
    Ls[qw][l31] = __builtin_amdgcn_rcpf(tot2);
#pragma unroll
    for (int j = 0; j < 16; ++j) {
      acc0[j] += cb[base + j];
      acc1[j] += cb[base + j + 16];
    }
#pragma unroll
    for (int j = 0; j < 16; ++j) {
      int row = (j & 3) + 8 * (j >> 2) + 4 * hfw;
      float inv = Ls[qw][row];
      size_t off = (size_t)(qblk * BQ + qw * 32 + row) * DH + l31;
      Ob[off]      = acc0[j] * inv;
      Ob[off + 32] = acc1[j] * inv;
    }
  }
}

extern "C" void kernel_launch(void* const* d_in, const int* in_sizes, int n_in,
                              void* d_out, int out_size, void* d_ws, size_t ws_size,
                              hipStream_t stream) {
  (void)in_sizes; (void)n_in; (void)ws_size; (void)out_size;
  const float* q = (const float*)d_in[0];
  const float* k = (const float*)d_in[1];
  const float* v = (const float*)d_in[2];
  float* o = (float*)d_out;
  // ws: Kh 9.44 MB | Vh 9.44 MB  (~18.9 MB total)
  _Float16* Kh = (_Float16*)d_ws;
  __bf16*   Vh = (__bf16*)((char*)d_ws + (size_t)32 * NT * TILEE * sizeof(_Float16));

  prepass<<<dim3(2 * 32 * NT), dim3(256), 0, stream>>>(k, v, Kh, Vh);
  flash_attn_v16<<<dim3(32 * (SEQ / BQ)), dim3(512), 0, stream>>>(q, Kh, Vh, o);
}